// Round 4
// baseline (262.338 us; speedup 1.0000x reference)
//
#include <hip/hip_runtime.h>

// Reference: damped harmonic oscillator, RK4, 4096 steps, batch 16384.
// INSIGHT 1: input x is unused except for batch size; all rows share
//   initial_state and (m,c,k) -> every output row is the SAME trajectory.
// INSIGHT 2: linear ODE -> one RK4 step is a fixed 2x2 matrix M (the RK4
//   stability polynomial). out[b][t] = pos-component of M^(t+1) s0, so the
//   "sequential" scan parallelizes via matrix powers (binary exponentiation).
// Round 3/4: single fused kernel (no d_ws round-trip, one launch). Each
//   thread computes its 4 trajectory steps in f64 (~230 FMA, hidden under
//   stores) and broadcasts its float4 to 16 output rows. Store-bound: 268 MB.

#define NUM_STEPS 4096
#define DT 0.01

struct dmat { double a, b, c, d; };   // [[a,b],[c,d]]

__device__ __forceinline__ dmat mmul(const dmat& x, const dmat& y) {
    dmat r;
    r.a = x.a * y.a + x.b * y.c;
    r.b = x.a * y.b + x.b * y.d;
    r.c = x.c * y.a + x.d * y.c;
    r.d = x.c * y.b + x.d * y.d;
    return r;
}

__global__ __launch_bounds__(256) void pinn_fused_kernel(
        const float* __restrict__ m_, const float* __restrict__ c_,
        const float* __restrict__ k_, const float* __restrict__ s0,
        float4* __restrict__ out4) {
    // Column tiling: 4096 steps = 1024 float4 columns; 4 blocks span a row,
    // each block owns 256 float4 columns and 16 rows.
    const int f  = ((blockIdx.x & 3) << 8) + threadIdx.x;   // float4 col 0..1023
    const int t0 = f << 2;                                  // first step index

    const double m = (double)m_[0];
    const double c = (double)c_[0];
    const double k = (double)k_[0];
    const double h = DT;
    const double a21 = -k / m, a22 = -c / m;

    dmat A  = {0.0, 1.0, a21, a22};
    dmat A2 = mmul(A, A);
    dmat A3 = mmul(A2, A);
    dmat A4 = mmul(A2, A2);
    const double h2 = h * h * 0.5;
    const double h3 = h * h * h / 6.0;
    const double h4 = h2 * h2 / 6.0;    // h^4/24
    // M = I + hA + h^2/2 A^2 + h^3/6 A^3 + h^4/24 A^4
    dmat M = {1.0 + h * A.a + h2 * A2.a + h3 * A3.a + h4 * A4.a,
                    h * A.b + h2 * A2.b + h3 * A3.b + h4 * A4.b,
                    h * A.c + h2 * A2.c + h3 * A3.c + h4 * A4.c,
              1.0 + h * A.d + h2 * A2.d + h3 * A3.d + h4 * A4.d};

    // R = M^(t0+1) by 13-bit binary exponentiation (t0+1 <= 4093)
    int e = t0 + 1;
    dmat R = {1.0, 0.0, 0.0, 1.0};
    dmat B = M;
    #pragma unroll
    for (int i = 0; i < 13; ++i) {
        if ((e >> i) & 1) R = mmul(R, B);
        B = mmul(B, B);
    }

    // state at step t0, then 3 sequential M-applies for t0+1..t0+3
    double sx = R.a * (double)s0[0] + R.b * (double)s0[1];
    double sv = R.c * (double)s0[0] + R.d * (double)s0[1];
    float4 v;
    v.x = (float)sx;
    double nx = M.a * sx + M.b * sv, nv = M.c * sx + M.d * sv;
    v.y = (float)nx;
    sx = M.a * nx + M.b * nv; sv = M.c * nx + M.d * nv;
    v.z = (float)sx;
    nx = M.a * sx + M.b * sv;
    v.w = (float)nx;

    // Broadcast to 16 rows: fully coalesced 1 KiB/wave stores, stride 16 KiB.
    float4* p = out4 + (size_t)(blockIdx.x >> 2) * 16 * 1024 + f;
    #pragma unroll
    for (int i = 0; i < 16; ++i)
        p[(size_t)i * 1024] = v;
}

extern "C" void kernel_launch(void* const* d_in, const int* in_sizes, int n_in,
                              void* d_out, int out_size, void* d_ws, size_t ws_size,
                              hipStream_t stream) {
    // inputs: x(16384*2) [unused], m(1), c(1), k(1), initial_state(2)
    const float* m_ = (const float*)d_in[1];
    const float* c_ = (const float*)d_in[2];
    const float* k_ = (const float*)d_in[3];
    const float* s0 = (const float*)d_in[4];
    float4* out4 = (float4*)d_out;              // 16384 x 4096 floats

    // 16384 rows / 16 rows-per-block * 4 col-blocks = 4096 blocks
    pinn_fused_kernel<<<4096, 256, 0, stream>>>(m_, c_, k_, s0, out4);
}